// Round 10
// baseline (441.888 us; speedup 1.0000x reference)
//
#include <hip/hip_runtime.h>

#define NW 2048
#define NS 8192
#define NSL 128            // slices of 16 rows; slice = 16*2048 u16 = 64 KB LDS

typedef int            i32x4 __attribute__((ext_vector_type(4)));
typedef unsigned int   u32x4 __attribute__((ext_vector_type(4)));
typedef float          f32x4 __attribute__((ext_vector_type(4)));
typedef unsigned short u16x4 __attribute__((ext_vector_type(4)));

// 16-lane sum reduce via DPP row_shr (VALU-only); full sum lands in lane 15.
__device__ __forceinline__ unsigned red16(unsigned x) {
    x += (unsigned)__builtin_amdgcn_update_dpp(0, (int)x, 0x111, 0xF, 0xF, true); // row_shr:1
    x += (unsigned)__builtin_amdgcn_update_dpp(0, (int)x, 0x112, 0xF, 0xF, true); // row_shr:2
    x += (unsigned)__builtin_amdgcn_update_dpp(0, (int)x, 0x114, 0xF, 0xF, true); // row_shr:4
    x += (unsigned)__builtin_amdgcn_update_dpp(0, (int)x, 0x118, 0xF, 0xF, true); // row_shr:8
    return x;   // valid in lane 15 of each row
}

// ============================ PRIMARY PATH =================================
// A: fused prep. Blocks [0,2048): build 8-bit packed table
//    cell = (round(bias*255)<<8)|round(bigram*255).
//    Blocks [2048,4096): bucket 4 samples each (wave-per-sample), writing
//    bucketed keys + packed (cnt<<16)|off + first/last, zeroing acc + counter.
__global__ __launch_bounds__(256) void prep_kernel(
    const f32x4* __restrict__ g, const f32x4* __restrict__ b,
    u16x4* __restrict__ tab4,
    const i32x4* __restrict__ samples4,
    unsigned short* __restrict__ gkeys,        // NS * 2048
    unsigned* __restrict__ oc_s,               // NS * 128, (cnt<<16)|off
    int* __restrict__ fl,                      // NS * 2
    unsigned long long* __restrict__ acc,      // NS (zeroed here)
    unsigned* __restrict__ dcnt)               // done-counter (zeroed here)
{
    __shared__ unsigned short srow[4][NW];
    __shared__ unsigned short kbuf[4][NW];
    __shared__ unsigned hist[4][NSL];
    __shared__ unsigned cur[4][NSL];
    const int t = threadIdx.x;

    if (blockIdx.x < 2048) {                   // ---- table build ----
        int i = blockIdx.x * 256 + t;
#pragma unroll
        for (int rep = 0; rep < 2; ++rep, i += 2048 * 256) {
            f32x4 gg = __builtin_nontemporal_load(&g[i]);
            f32x4 bb = __builtin_nontemporal_load(&b[i]);
            u16x4 o;
            o.x = (unsigned short)((__float2uint_rn(bb.x * 255.f) << 8) | __float2uint_rn(gg.x * 255.f));
            o.y = (unsigned short)((__float2uint_rn(bb.y * 255.f) << 8) | __float2uint_rn(gg.y * 255.f));
            o.z = (unsigned short)((__float2uint_rn(bb.z * 255.f) << 8) | __float2uint_rn(gg.z * 255.f));
            o.w = (unsigned short)((__float2uint_rn(bb.w * 255.f) << 8) | __float2uint_rn(gg.w * 255.f));
            __builtin_nontemporal_store(o, &tab4[i]);
        }
        if (blockIdx.x == 0 && t == 0) *dcnt = 0;
        return;
    }

    // ---- bucketing ----
    const int w = t >> 6, l = t & 63;
    const int s = (blockIdx.x - 2048) * 4 + w;

    const i32x4* rp = samples4 + (size_t)s * (NW / 4);
#pragma unroll
    for (int k = 0; k < 8; ++k) {
        i32x4 v = __builtin_nontemporal_load(&rp[l + 64 * k]);
        u16x4 o;
        o.x = (unsigned short)v.x; o.y = (unsigned short)v.y;
        o.z = (unsigned short)v.z; o.w = (unsigned short)v.w;
        ((u16x4*)srow[w])[l + 64 * k] = o;
    }
    hist[w][l] = 0; hist[w][l + 64] = 0;
    __syncthreads();

#pragma unroll
    for (int k = 0; k < 32; ++k) {
        int j = l + 64 * k;
        if (j < NW - 1) atomicAdd(&hist[w][srow[w][j] >> 4], 1u);
    }
    __syncthreads();

    unsigned c0 = hist[w][l], c1 = hist[w][l + 64];
    unsigned x0 = c0, x1 = c1;
#pragma unroll
    for (int d = 1; d < 64; d <<= 1) {
        unsigned y0 = __shfl_up(x0, d);
        unsigned y1 = __shfl_up(x1, d);
        if (l >= d) { x0 += y0; x1 += y1; }
    }
    unsigned tot0 = __shfl(x0, 63);
    unsigned off0 = x0 - c0;
    unsigned off1 = tot0 + x1 - c1;
    cur[w][l] = off0; cur[w][l + 64] = off1;
    __syncthreads();

#pragma unroll
    for (int k = 0; k < 32; ++k) {
        int j = l + 64 * k;
        if (j < NW - 1) {
            unsigned r = srow[w][j], c = srow[w][j + 1];
            unsigned pos = atomicAdd(&cur[w][r >> 4], 1u);
            kbuf[w][pos] = (unsigned short)(((r & 15u) << 11) | c);
        }
    }
    __syncthreads();

#pragma unroll
    for (int k = 0; k < 4; ++k)
        __builtin_nontemporal_store(((u32x4*)kbuf[w])[l + 64 * k],
                                    &((u32x4*)(gkeys + (size_t)s * NW))[l + 64 * k]);
    oc_s[(size_t)s * NSL + l]      = (c0 << 16) | off0;
    oc_s[(size_t)s * NSL + l + 64] = (c1 << 16) | off1;
    if (l == 0) {
        fl[2 * s] = (int)srow[w][0];
        fl[2 * s + 1] = (int)srow[w][NW - 1];
        acc[s] = 0ull;
    }
}

// B: LDS-table gather + inline last-block finalize.
//  - slice q (64 KB) staged in LDS (cacheable loads: L2 reuse across chunks);
//  - oc read directly from oc_s[s][bin]: with bin=((q&7)<<4)|(q>>3), XCD x
//    needs exactly one 64B oc-line per sample -> L2-hits 15/16;
//  - batched ocr broadcasts + 2-deep key prefetch (covers cnt<=32, P>32~1e-4);
//  - DPP reduce, lane-15 u64 atomic;
//  - last block (agent-scope counter) reads acc via agent-scope atomic loads
//    (cross-XCD safe) and computes the final loss.
__global__ __launch_bounds__(1024) void gather7_kernel(
    const unsigned short* __restrict__ tab,
    const unsigned short* __restrict__ gkeys,
    const unsigned* __restrict__ oc_s,
    const int* __restrict__ fl,
    const float* __restrict__ bigram, const float* __restrict__ bias,
    const float* __restrict__ start, const float* __restrict__ endv,
    unsigned long long* __restrict__ acc,
    unsigned* __restrict__ dcnt,
    float* __restrict__ out)
{
    __shared__ unsigned short stab[16 * NW];      // 64 KB
    __shared__ unsigned sdone;
    const int q = blockIdx.x;
    const int bin = ((q & 7) << 4) | (q >> 3);    // XCD-contiguous bin mapping
    const int chunk = blockIdx.y;
    const int t = threadIdx.x, w = t >> 6, l = t & 63;

    const u32x4* srcp = (const u32x4*)(tab + (size_t)bin * 16 * NW);
    u32x4* dstp = (u32x4*)stab;
#pragma unroll
    for (int k = 0; k < 4; ++k)
        dstp[t + 1024 * k] = srcp[t + 1024 * k];

    const int sbase = chunk * 1024 + w * 64;
    unsigned oc = oc_s[(size_t)(sbase + l) * NSL + bin];   // strided, L2-local line
    __syncthreads();

    const int g = l >> 4, li = l & 15;
    const unsigned short* keyrow = gkeys + (size_t)sbase * NW;

#pragma unroll
    for (int batch = 0; batch < 2; ++batch) {
        unsigned ocr[8];
        unsigned short key[8], key2[8];
#pragma unroll
        for (int r8 = 0; r8 < 8; ++r8)
            ocr[r8] = __shfl(oc, (batch * 8 + r8) * 4 + g);
#pragma unroll
        for (int r8 = 0; r8 < 8; ++r8) {
            int sid = (batch * 8 + r8) * 4 + g;
            unsigned off = ocr[r8] & 0xffffu, cnt = ocr[r8] >> 16;
            const unsigned short* kp = keyrow + (size_t)sid * NW + off;
            key[r8]  = (li < (int)cnt)      ? kp[li]      : (unsigned short)0;
            key2[r8] = (li + 16 < (int)cnt) ? kp[li + 16] : (unsigned short)0;
        }
#pragma unroll
        for (int r8 = 0; r8 < 8; ++r8) {
            int sid = (batch * 8 + r8) * 4 + g;
            unsigned off = ocr[r8] & 0xffffu, cnt = ocr[r8] >> 16;
            unsigned gs = 0, bs = 0;
            if (li < (int)cnt)      { unsigned v = stab[key[r8]];  gs += v & 0xffu; bs += v >> 8; }
            if (li + 16 < (int)cnt) { unsigned v = stab[key2[r8]]; gs += v & 0xffu; bs += v >> 8; }
            for (unsigned p = (unsigned)li + 32; p < cnt; p += 16) {
                unsigned v = stab[keyrow[(size_t)sid * NW + off + p]];
                gs += v & 0xffu; bs += v >> 8;
            }
            gs = red16(gs);
            bs = red16(bs);
            if (li == 15)
                atomicAdd(&acc[sbase + sid],
                          ((unsigned long long)bs << 32) | (unsigned long long)gs);
        }
    }

    // -------- last-block finalize --------
    __threadfence();
    if (t == 0) {
        unsigned old = __hip_atomic_fetch_add(dcnt, 1u, __ATOMIC_ACQ_REL,
                                              __HIP_MEMORY_SCOPE_AGENT);
        sdone = (old == (unsigned)(NSL * (NS / 1024)) - 1u);
    }
    __syncthreads();
    if (!sdone) return;

    double su = 0.0, sw = 0.0, diag = 0.0;
    for (int s = t; s < NS; s += 1024) {
        unsigned long long a = __hip_atomic_load(&acc[s], __ATOMIC_RELAXED,
                                                 __HIP_MEMORY_SCOPE_AGENT);
        double u = (double)(unsigned)(a & 0xffffffffu) * (1.0 / 255.0)
                 + (double)start[fl[2 * s]] + (double)endv[fl[2 * s + 1]];
        double bb = (double)(unsigned)(a >> 32) * (1.0 / 255.0);
        su += u;
        sw += u * (u + bb);
    }
    for (int k = t; k < NW - 1; k += 1024) {
        size_t idx = (size_t)k * NW + (size_t)k + 1;
        diag += (double)bigram[idx] + (double)bias[idx];
    }
#pragma unroll
    for (int o = 32; o; o >>= 1) {
        su   += __shfl_down(su, o);
        sw   += __shfl_down(sw, o);
        diag += __shfl_down(diag, o);
    }
    double* shd = (double*)stab;                 // reuse LDS (gather done)
    if ((t & 63) == 0) {
        int ww = t >> 6;
        shd[3 * ww] = su; shd[3 * ww + 1] = sw; shd[3 * ww + 2] = diag;
    }
    __syncthreads();
    if (t == 0) {
        for (int ww = 1; ww < 16; ++ww) {
            su += shd[3 * ww]; sw += shd[3 * ww + 1]; diag += shd[3 * ww + 2];
        }
        double C = (double)start[0] + (double)endv[NW - 1] + diag;
        out[0] = (float)(sw / su - C);
    }
}

// ====================== FALLBACK (round-1 structure) ========================
__global__ __launch_bounds__(256) void interleave_kernel(
    const float* __restrict__ bigram, const float* __restrict__ bias,
    float2* __restrict__ comb)
{
    size_t total = (size_t)NW * NW;
    size_t stride = (size_t)gridDim.x * blockDim.x;
    for (size_t i = (size_t)blockIdx.x * blockDim.x + threadIdx.x; i < total; i += stride)
        comb[i] = make_float2(bigram[i], bias[i]);
}

template <bool USE_COMB>
__global__ __launch_bounds__(256) void sample_kernel(
    const float2* __restrict__ comb,
    const float* __restrict__ bigram, const float* __restrict__ bias,
    const float* __restrict__ start, const float* __restrict__ endv,
    const int* __restrict__ samples,
    float* __restrict__ u_out, float* __restrict__ b_out)
{
    __shared__ int srow[NW];
    __shared__ float su[4], sb[4];
    const int i = blockIdx.x;
    const int t = threadIdx.x;
    const int4* row4 = (const int4*)(samples + (size_t)i * NW);
    int4* srow4 = (int4*)srow;
    srow4[t]       = row4[t];
    srow4[t + 256] = row4[t + 256];
    __syncthreads();
    float u = 0.f, b = 0.f;
#pragma unroll
    for (int k = 0; k < 8; ++k) {
        int j = t + k * 256;
        if (j < NW - 1) {
            int r = srow[j], c = srow[j + 1];
            size_t idx = ((size_t)r << 11) + (size_t)c;
            if (USE_COMB) { float2 v = comb[idx]; u += v.x; b += v.y; }
            else          { u += bigram[idx]; b += bias[idx]; }
        }
    }
#pragma unroll
    for (int off = 32; off; off >>= 1) {
        u += __shfl_down(u, off);
        b += __shfl_down(b, off);
    }
    if ((t & 63) == 0) { su[t >> 6] = u; sb[t >> 6] = b; }
    __syncthreads();
    if (t == 0) {
        u = su[0] + su[1] + su[2] + su[3];
        b = sb[0] + sb[1] + sb[2] + sb[3];
        u += start[srow[0]] + endv[srow[NW - 1]];
        u_out[i] = u;
        b_out[i] = b;
    }
}

__global__ __launch_bounds__(1024) void finalize_kernel(
    const float* __restrict__ bigram, const float* __restrict__ bias,
    const float* __restrict__ start, const float* __restrict__ endv,
    const float* __restrict__ u_in, const float* __restrict__ b_in,
    float* __restrict__ out)
{
    const int t = threadIdx.x;
    double su = 0.0, sw = 0.0, diag = 0.0;
    for (int i = t; i < NS; i += 1024) {
        double u = (double)u_in[i];
        su += u;
        sw += u * (u + (double)b_in[i]);
    }
    for (int k = t; k < NW - 1; k += 1024) {
        size_t idx = (size_t)k * NW + (size_t)k + 1;
        diag += (double)bigram[idx] + (double)bias[idx];
    }
#pragma unroll
    for (int off = 32; off; off >>= 1) {
        su   += __shfl_down(su, off);
        sw   += __shfl_down(sw, off);
        diag += __shfl_down(diag, off);
    }
    __shared__ double s1[16], s2[16], s3[16];
    if ((t & 63) == 0) { int w = t >> 6; s1[w] = su; s2[w] = sw; s3[w] = diag; }
    __syncthreads();
    if (t == 0) {
        for (int w = 1; w < 16; ++w) { su += s1[w]; sw += s2[w]; diag += s3[w]; }
        double C = (double)start[0] + (double)endv[NW - 1] + diag;
        out[0] = (float)(sw / su - C);
    }
}

// ===========================================================================
extern "C" void kernel_launch(void* const* d_in, const int* in_sizes, int n_in,
                              void* d_out, int out_size, void* d_ws, size_t ws_size,
                              hipStream_t stream) {
    const float* bigram  = (const float*)d_in[0];
    const float* start   = (const float*)d_in[1];
    const float* endv    = (const float*)d_in[2];
    const float* bias    = (const float*)d_in[3];
    const int*   samples = (const int*)d_in[4];
    float* out = (float*)d_out;

    // primary ws layout
    size_t off = 0;
    size_t tab_off  = off; off += (size_t)NW * NW * 2;    // 8 MB u16 table
    off = (off + 255) & ~(size_t)255;
    size_t keys_off = off; off += (size_t)NS * NW * 2;    // 32 MB u16 keys
    off = (off + 255) & ~(size_t)255;
    size_t ocs_off  = off; off += (size_t)NS * NSL * 4;   // 4 MB oc sample-major
    off = (off + 255) & ~(size_t)255;
    size_t fl_off   = off; off += (size_t)NS * 2 * 4;     // 64 KB first/last
    off = (off + 255) & ~(size_t)255;
    size_t acc_off  = off; off += (size_t)NS * 8;         // 64 KB packed acc
    off = (off + 255) & ~(size_t)255;
    size_t cnt_off  = off; off += 256;                    // done counter
    size_t need_primary = off;

    if (ws_size >= need_primary) {
        unsigned short*     tab   = (unsigned short*)((char*)d_ws + tab_off);
        unsigned short*     gkeys = (unsigned short*)((char*)d_ws + keys_off);
        unsigned*           oc_s  = (unsigned*)((char*)d_ws + ocs_off);
        int*                fl    = (int*)((char*)d_ws + fl_off);
        unsigned long long* acc   = (unsigned long long*)((char*)d_ws + acc_off);
        unsigned*           dcnt  = (unsigned*)((char*)d_ws + cnt_off);

        prep_kernel<<<4096, 256, 0, stream>>>(
            (const f32x4*)bigram, (const f32x4*)bias, (u16x4*)tab,
            (const i32x4*)samples, gkeys, oc_s, fl, acc, dcnt);
        gather7_kernel<<<dim3(NSL, NS / 1024), 1024, 0, stream>>>(
            tab, gkeys, oc_s, fl, bigram, bias, start, endv, acc, dcnt, out);
        return;
    }

    // fallback: round-1 structure
    float* u_out = (float*)d_ws;
    float* b_out = u_out + NS;
    size_t comb_off = ((size_t)NS * 2 * sizeof(float) + 255) & ~(size_t)255;
    size_t comb_bytes = (size_t)NW * NW * sizeof(float2);
    bool use_comb = (ws_size >= comb_off + comb_bytes);
    if (use_comb) {
        float2* comb = (float2*)((char*)d_ws + comb_off);
        interleave_kernel<<<4096, 256, 0, stream>>>(bigram, bias, comb);
        sample_kernel<true><<<NS, 256, 0, stream>>>(comb, bigram, bias, start, endv,
                                                    samples, u_out, b_out);
    } else {
        sample_kernel<false><<<NS, 256, 0, stream>>>(nullptr, bigram, bias, start, endv,
                                                     samples, u_out, b_out);
    }
    finalize_kernel<<<1, 1024, 0, stream>>>(bigram, bias, start, endv, u_out, b_out, out);
}

// Round 11
// 236.845 us; speedup vs baseline: 1.8657x; 1.8657x over previous
//
#include <hip/hip_runtime.h>

#define NW 2048
#define NS 8192
#define NSL 128            // slices of 16 rows; slice = 16*2048 u16 = 64 KB LDS

typedef int            i32x4 __attribute__((ext_vector_type(4)));
typedef unsigned int   u32x4 __attribute__((ext_vector_type(4)));
typedef float          f32x4 __attribute__((ext_vector_type(4)));
typedef unsigned short u16x4 __attribute__((ext_vector_type(4)));

// 16-lane sum reduce via DPP row_shr (VALU-only); full sum lands in lane 15.
__device__ __forceinline__ unsigned red16(unsigned x) {
    x += (unsigned)__builtin_amdgcn_update_dpp(0, (int)x, 0x111, 0xF, 0xF, true); // row_shr:1
    x += (unsigned)__builtin_amdgcn_update_dpp(0, (int)x, 0x112, 0xF, 0xF, true); // row_shr:2
    x += (unsigned)__builtin_amdgcn_update_dpp(0, (int)x, 0x114, 0xF, 0xF, true); // row_shr:4
    x += (unsigned)__builtin_amdgcn_update_dpp(0, (int)x, 0x118, 0xF, 0xF, true); // row_shr:8
    return x;   // valid in lane 15 of each row
}

// acc[s] packing: [count:8][bs:28][gs:28]; per-bin add = (1<<56)|(bs<<28)|gs.
// gs,bs <= 2047*255 < 2^19, so 128 adds never overflow a 28-bit field.

// ============================ PRIMARY PATH =================================
// A: fused prep. Blocks [0,2048): build 8-bit packed table + superdiagonal
//    fp64 partial (device atomics into diag slot -- zeroed by block 0's plain
//    store is a race, so diag is NOT zeroed here; see slots note below).
//    Blocks [2048,4096): bucket 4 samples each; zero acc.
// Slots (su,sw,diag,scnt) are zeroed by block 0 with plain stores; they are
// only atomically updated in dispatch 2 (kernel boundary orders them), EXCEPT
// diag which prep itself atomically updates -> race with block 0's zeroing.
// Fix: diag contributions go to a SEPARATE slot pair: prep's table blocks
// atomically add into diag_p which block 0 zeroes FIRST? still racy.
// => diag is computed entirely in dispatch 2 (block 0 after its gather work).
__global__ __launch_bounds__(256) void prep_kernel(
    const f32x4* __restrict__ g, const f32x4* __restrict__ b,
    u16x4* __restrict__ tab4,
    const i32x4* __restrict__ samples4,
    unsigned short* __restrict__ gkeys,        // NS * 2048
    unsigned* __restrict__ oc_s,               // NS * 128, (cnt<<16)|off
    int* __restrict__ fl,                      // NS * 2
    unsigned long long* __restrict__ acc,      // NS (zeroed here)
    double* __restrict__ slots)                // [su, sw, diag] f64 + scnt u64
{
    __shared__ unsigned short srow[4][NW];
    __shared__ unsigned short kbuf[4][NW];
    __shared__ unsigned hist[4][NSL];
    __shared__ unsigned cur[4][NSL];
    const int t = threadIdx.x;

    if (blockIdx.x < 2048) {                   // ---- table build ----
        int i = blockIdx.x * 256 + t;
#pragma unroll
        for (int rep = 0; rep < 2; ++rep, i += 2048 * 256) {
            f32x4 gg = __builtin_nontemporal_load(&g[i]);
            f32x4 bb = __builtin_nontemporal_load(&b[i]);
            u16x4 o;
            o.x = (unsigned short)((__float2uint_rn(bb.x * 255.f) << 8) | __float2uint_rn(gg.x * 255.f));
            o.y = (unsigned short)((__float2uint_rn(bb.y * 255.f) << 8) | __float2uint_rn(gg.y * 255.f));
            o.z = (unsigned short)((__float2uint_rn(bb.z * 255.f) << 8) | __float2uint_rn(gg.z * 255.f));
            o.w = (unsigned short)((__float2uint_rn(bb.w * 255.f) << 8) | __float2uint_rn(gg.w * 255.f));
            __builtin_nontemporal_store(o, &tab4[i]);
        }
        if (blockIdx.x == 0 && t < 4) slots[t] = 0.0;   // su, sw, diag, scnt
        return;
    }

    // ---- bucketing (wave-per-sample) ----
    const int w = t >> 6, l = t & 63;
    const int s = (blockIdx.x - 2048) * 4 + w;

    const i32x4* rp = samples4 + (size_t)s * (NW / 4);
#pragma unroll
    for (int k = 0; k < 8; ++k) {
        i32x4 v = __builtin_nontemporal_load(&rp[l + 64 * k]);
        u16x4 o;
        o.x = (unsigned short)v.x; o.y = (unsigned short)v.y;
        o.z = (unsigned short)v.z; o.w = (unsigned short)v.w;
        ((u16x4*)srow[w])[l + 64 * k] = o;
    }
    hist[w][l] = 0; hist[w][l + 64] = 0;
    __syncthreads();

#pragma unroll
    for (int k = 0; k < 32; ++k) {
        int j = l + 64 * k;
        if (j < NW - 1) atomicAdd(&hist[w][srow[w][j] >> 4], 1u);
    }
    __syncthreads();

    unsigned c0 = hist[w][l], c1 = hist[w][l + 64];
    unsigned x0 = c0, x1 = c1;
#pragma unroll
    for (int d = 1; d < 64; d <<= 1) {
        unsigned y0 = __shfl_up(x0, d);
        unsigned y1 = __shfl_up(x1, d);
        if (l >= d) { x0 += y0; x1 += y1; }
    }
    unsigned tot0 = __shfl(x0, 63);
    unsigned off0 = x0 - c0;
    unsigned off1 = tot0 + x1 - c1;
    cur[w][l] = off0; cur[w][l + 64] = off1;
    __syncthreads();

#pragma unroll
    for (int k = 0; k < 32; ++k) {
        int j = l + 64 * k;
        if (j < NW - 1) {
            unsigned r = srow[w][j], c = srow[w][j + 1];
            unsigned pos = atomicAdd(&cur[w][r >> 4], 1u);
            kbuf[w][pos] = (unsigned short)(((r & 15u) << 11) | c);
        }
    }
    __syncthreads();

#pragma unroll
    for (int k = 0; k < 4; ++k)
        __builtin_nontemporal_store(((u32x4*)kbuf[w])[l + 64 * k],
                                    &((u32x4*)(gkeys + (size_t)s * NW))[l + 64 * k]);
    oc_s[(size_t)s * NSL + l]      = (c0 << 16) | off0;
    oc_s[(size_t)s * NSL + l + 64] = (c1 << 16) | off1;
    if (l == 0) {
        fl[2 * s] = (int)srow[w][0];
        fl[2 * s + 1] = (int)srow[w][NW - 1];
        acc[s] = 0ull;
    }
}

// final combine, callable by whichever thread makes the 8193rd increment
__device__ __forceinline__ void grand_final(
    double* slots, const float* start, const float* endv, float* out)
{
    double su = atomicAdd(&slots[0], 0.0);
    double sw = atomicAdd(&slots[1], 0.0);
    double dg = atomicAdd(&slots[2], 0.0);
    double C = (double)start[0] + (double)endv[NW - 1] + dg;
    out[0] = (float)(sw / su - C);
}

// B: LDS-table gather, fence-free fused finalize.
//  - slice bin (64 KB) staged in LDS via cacheable loads (L2 reuse);
//  - oc read strided from oc_s: bins [16x,16x+16) of XCD x share ONE 64B
//    oc-line per sample -> L2-hits 15/16;
//  - per-bin lane-15 atomicAdd WITH RETURN into packed acc; old count==127
//    => this thread completes the sample: re-read stable total, fp64
//    atomicAdd into su/sw, s_waitcnt, bump grand counter;
//  - block (q=0,chunk=0) additionally computes the superdiagonal (fp64) and
//    contributes the 8193rd counter bump;
//  - 8193rd increment computes the loss. NO fences anywhere.
__global__ __launch_bounds__(1024) void gather8_kernel(
    const unsigned short* __restrict__ tab,
    const unsigned short* __restrict__ gkeys,
    const unsigned* __restrict__ oc_s,
    const int* __restrict__ fl,
    const float* __restrict__ bigram, const float* __restrict__ bias,
    const float* __restrict__ start, const float* __restrict__ endv,
    unsigned long long* __restrict__ acc,
    double* __restrict__ slots,
    float* __restrict__ out)
{
    __shared__ unsigned short stab[16 * NW];      // exactly 64 KB
    const int q = blockIdx.x;
    const int bin = ((q & 7) << 4) | (q >> 3);    // XCD-contiguous bin mapping
    const int chunk = blockIdx.y;
    const int t = threadIdx.x, w = t >> 6, l = t & 63;
    unsigned long long* scnt = (unsigned long long*)&slots[3];

    const u32x4* srcp = (const u32x4*)(tab + (size_t)bin * 16 * NW);
    u32x4* dstp = (u32x4*)stab;
#pragma unroll
    for (int k = 0; k < 4; ++k)
        dstp[t + 1024 * k] = srcp[t + 1024 * k];

    const int sbase = chunk * 1024 + w * 64;
    unsigned oc = oc_s[(size_t)(sbase + l) * NSL + bin];   // one L2 line/sample/XCD
    __syncthreads();

    const int g = l >> 4, li = l & 15;
    const unsigned short* keyrow = gkeys + (size_t)sbase * NW;

#pragma unroll
    for (int batch = 0; batch < 2; ++batch) {
        unsigned ocr[8];
        unsigned short key[8], key2[8];
        unsigned long long ret[8];
#pragma unroll
        for (int r8 = 0; r8 < 8; ++r8)
            ocr[r8] = __shfl(oc, (batch * 8 + r8) * 4 + g);
#pragma unroll
        for (int r8 = 0; r8 < 8; ++r8) {
            int sid = (batch * 8 + r8) * 4 + g;
            unsigned off = ocr[r8] & 0xffffu, cnt = ocr[r8] >> 16;
            const unsigned short* kp = keyrow + (size_t)sid * NW + off;
            key[r8]  = (li < (int)cnt)      ? kp[li]      : (unsigned short)0;
            key2[r8] = (li + 16 < (int)cnt) ? kp[li + 16] : (unsigned short)0;
        }
#pragma unroll
        for (int r8 = 0; r8 < 8; ++r8) {
            int sid = (batch * 8 + r8) * 4 + g;
            unsigned off = ocr[r8] & 0xffffu, cnt = ocr[r8] >> 16;
            unsigned gs = 0, bs = 0;
            if (li < (int)cnt)      { unsigned v = stab[key[r8]];  gs += v & 0xffu; bs += v >> 8; }
            if (li + 16 < (int)cnt) { unsigned v = stab[key2[r8]]; gs += v & 0xffu; bs += v >> 8; }
            for (unsigned p = (unsigned)li + 32; p < cnt; p += 16) {
                unsigned v = stab[keyrow[(size_t)sid * NW + off + p]];
                gs += v & 0xffu; bs += v >> 8;
            }
            gs = red16(gs);
            bs = red16(bs);
            ret[r8] = 0ull;
            if (li == 15)
                ret[r8] = atomicAdd(&acc[sbase + sid],
                                    (1ull << 56) | ((unsigned long long)bs << 28)
                                                 | (unsigned long long)gs);
        }
        // completion checks (returns drained together; rare path)
#pragma unroll
        for (int r8 = 0; r8 < 8; ++r8) {
            if (li == 15 && (ret[r8] >> 56) == 127ull) {
                int sg = sbase + (batch * 8 + r8) * 4 + g;
                unsigned long long fin = atomicAdd(&acc[sg], 0ull);  // stable now
                double gt = (double)(unsigned)(fin & 0xFFFFFFFu);
                double bt = (double)(unsigned)((fin >> 28) & 0xFFFFFFFu);
                double u = gt * (1.0 / 255.0)
                         + (double)start[fl[2 * sg]] + (double)endv[fl[2 * sg + 1]];
                double bb = bt * (1.0 / 255.0);
                atomicAdd(&slots[0], u);
                atomicAdd(&slots[1], u * (u + bb));
                __builtin_amdgcn_s_waitcnt(0);       // drain (no cache maintenance)
                unsigned long long c = atomicAdd(scnt, 1ull);
                if (c == (unsigned long long)NS)     // 8193rd increment -> final
                    grand_final(slots, start, endv, out);
            }
        }
    }

    // -------- superdiagonal (block q=0,chunk=0 only) --------
    if (q == 0 && chunk == 0) {
        double d = 0.0;
        for (int k = t; k < NW - 1; k += 1024) {
            size_t idx = (size_t)k * NW + (size_t)k + 1;
            d += (double)bigram[idx] + (double)bias[idx];
        }
#pragma unroll
        for (int o = 32; o; o >>= 1) d += __shfl_down(d, o);
        if ((t & 63) == 0) atomicAdd(&slots[2], d);
        __builtin_amdgcn_s_waitcnt(0);
        __syncthreads();                             // all 16 wave-adds drained
        if (t == 0) {
            unsigned long long c = atomicAdd(scnt, 1ull);
            if (c == (unsigned long long)NS)
                grand_final(slots, start, endv, out);
        }
    }
}

// ====================== FALLBACK (round-1 structure) ========================
__global__ __launch_bounds__(256) void interleave_kernel(
    const float* __restrict__ bigram, const float* __restrict__ bias,
    float2* __restrict__ comb)
{
    size_t total = (size_t)NW * NW;
    size_t stride = (size_t)gridDim.x * blockDim.x;
    for (size_t i = (size_t)blockIdx.x * blockDim.x + threadIdx.x; i < total; i += stride)
        comb[i] = make_float2(bigram[i], bias[i]);
}

template <bool USE_COMB>
__global__ __launch_bounds__(256) void sample_kernel(
    const float2* __restrict__ comb,
    const float* __restrict__ bigram, const float* __restrict__ bias,
    const float* __restrict__ start, const float* __restrict__ endv,
    const int* __restrict__ samples,
    float* __restrict__ u_out, float* __restrict__ b_out)
{
    __shared__ int srow[NW];
    __shared__ float su[4], sb[4];
    const int i = blockIdx.x;
    const int t = threadIdx.x;
    const int4* row4 = (const int4*)(samples + (size_t)i * NW);
    int4* srow4 = (int4*)srow;
    srow4[t]       = row4[t];
    srow4[t + 256] = row4[t + 256];
    __syncthreads();
    float u = 0.f, b = 0.f;
#pragma unroll
    for (int k = 0; k < 8; ++k) {
        int j = t + k * 256;
        if (j < NW - 1) {
            int r = srow[j], c = srow[j + 1];
            size_t idx = ((size_t)r << 11) + (size_t)c;
            if (USE_COMB) { float2 v = comb[idx]; u += v.x; b += v.y; }
            else          { u += bigram[idx]; b += bias[idx]; }
        }
    }
#pragma unroll
    for (int off = 32; off; off >>= 1) {
        u += __shfl_down(u, off);
        b += __shfl_down(b, off);
    }
    if ((t & 63) == 0) { su[t >> 6] = u; sb[t >> 6] = b; }
    __syncthreads();
    if (t == 0) {
        u = su[0] + su[1] + su[2] + su[3];
        b = sb[0] + sb[1] + sb[2] + sb[3];
        u += start[srow[0]] + endv[srow[NW - 1]];
        u_out[i] = u;
        b_out[i] = b;
    }
}

__global__ __launch_bounds__(1024) void finalize_kernel(
    const float* __restrict__ bigram, const float* __restrict__ bias,
    const float* __restrict__ start, const float* __restrict__ endv,
    const float* __restrict__ u_in, const float* __restrict__ b_in,
    float* __restrict__ out)
{
    const int t = threadIdx.x;
    double su = 0.0, sw = 0.0, diag = 0.0;
    for (int i = t; i < NS; i += 1024) {
        double u = (double)u_in[i];
        su += u;
        sw += u * (u + (double)b_in[i]);
    }
    for (int k = t; k < NW - 1; k += 1024) {
        size_t idx = (size_t)k * NW + (size_t)k + 1;
        diag += (double)bigram[idx] + (double)bias[idx];
    }
#pragma unroll
    for (int off = 32; off; off >>= 1) {
        su   += __shfl_down(su, off);
        sw   += __shfl_down(sw, off);
        diag += __shfl_down(diag, off);
    }
    __shared__ double s1[16], s2[16], s3[16];
    if ((t & 63) == 0) { int w = t >> 6; s1[w] = su; s2[w] = sw; s3[w] = diag; }
    __syncthreads();
    if (t == 0) {
        for (int w = 1; w < 16; ++w) { su += s1[w]; sw += s2[w]; diag += s3[w]; }
        double C = (double)start[0] + (double)endv[NW - 1] + diag;
        out[0] = (float)(sw / su - C);
    }
}

// ===========================================================================
extern "C" void kernel_launch(void* const* d_in, const int* in_sizes, int n_in,
                              void* d_out, int out_size, void* d_ws, size_t ws_size,
                              hipStream_t stream) {
    const float* bigram  = (const float*)d_in[0];
    const float* start   = (const float*)d_in[1];
    const float* endv    = (const float*)d_in[2];
    const float* bias    = (const float*)d_in[3];
    const int*   samples = (const int*)d_in[4];
    float* out = (float*)d_out;

    // primary ws layout
    size_t off = 0;
    size_t tab_off  = off; off += (size_t)NW * NW * 2;    // 8 MB u16 table
    off = (off + 255) & ~(size_t)255;
    size_t keys_off = off; off += (size_t)NS * NW * 2;    // 32 MB u16 keys
    off = (off + 255) & ~(size_t)255;
    size_t ocs_off  = off; off += (size_t)NS * NSL * 4;   // 4 MB oc sample-major
    off = (off + 255) & ~(size_t)255;
    size_t fl_off   = off; off += (size_t)NS * 2 * 4;     // 64 KB first/last
    off = (off + 255) & ~(size_t)255;
    size_t acc_off  = off; off += (size_t)NS * 8;         // 64 KB packed acc
    off = (off + 255) & ~(size_t)255;
    size_t slot_off = off; off += 256;                    // su/sw/diag/scnt
    size_t need_primary = off;

    if (ws_size >= need_primary) {
        unsigned short*     tab   = (unsigned short*)((char*)d_ws + tab_off);
        unsigned short*     gkeys = (unsigned short*)((char*)d_ws + keys_off);
        unsigned*           oc_s  = (unsigned*)((char*)d_ws + ocs_off);
        int*                fl    = (int*)((char*)d_ws + fl_off);
        unsigned long long* acc   = (unsigned long long*)((char*)d_ws + acc_off);
        double*             slots = (double*)((char*)d_ws + slot_off);

        prep_kernel<<<4096, 256, 0, stream>>>(
            (const f32x4*)bigram, (const f32x4*)bias, (u16x4*)tab,
            (const i32x4*)samples, gkeys, oc_s, fl, acc, slots);
        gather8_kernel<<<dim3(NSL, NS / 1024), 1024, 0, stream>>>(
            tab, gkeys, oc_s, fl, bigram, bias, start, endv, acc, slots, out);
        return;
    }

    // fallback: round-1 structure
    float* u_out = (float*)d_ws;
    float* b_out = u_out + NS;
    size_t comb_off = ((size_t)NS * 2 * sizeof(float) + 255) & ~(size_t)255;
    size_t comb_bytes = (size_t)NW * NW * sizeof(float2);
    bool use_comb = (ws_size >= comb_off + comb_bytes);
    if (use_comb) {
        float2* comb = (float2*)((char*)d_ws + comb_off);
        interleave_kernel<<<4096, 256, 0, stream>>>(bigram, bias, comb);
        sample_kernel<true><<<NS, 256, 0, stream>>>(comb, bigram, bias, start, endv,
                                                    samples, u_out, b_out);
    } else {
        sample_kernel<false><<<NS, 256, 0, stream>>>(nullptr, bigram, bias, start, endv,
                                                     samples, u_out, b_out);
    }
    finalize_kernel<<<1, 1024, 0, stream>>>(bigram, bias, start, endv, u_out, b_out, out);
}